// Round 7
// baseline (13039.571 us; speedup 1.0000x reference)
//
#include <hip/hip_runtime.h>

#define B_ 512
#define T_ 256
#define D_ 128
#define H_ 512

typedef __bf16 bf16x8 __attribute__((ext_vector_type(8)));
typedef float f32x4 __attribute__((ext_vector_type(4)));
typedef unsigned long long u64;

__device__ __forceinline__ float sigm(float x) { return 1.f / (1.f + __expf(-x)); }
__device__ __forceinline__ float tanh_(float x) { return 2.f / (1.f + __expf(-2.f * x)) - 1.f; }

__device__ __forceinline__ void split2(float v, __bf16& hi, __bf16& lo) {
    hi = (__bf16)v;
    lo = (__bf16)(v - (float)hi);
}

// coherent (agent-scope) 8B load/store: bypasses per-XCD L2, hits the coherent point.
__device__ __forceinline__ u64 cload(const __bf16* p) {
    return __hip_atomic_load((u64*)p, __ATOMIC_RELAXED, __HIP_MEMORY_SCOPE_AGENT);
}
__device__ __forceinline__ void cstore(__bf16* p, u64 v) {
    __hip_atomic_store((u64*)p, v, __ATOMIC_RELAXED, __HIP_MEMORY_SCOPE_AGENT);
}

// ---------------- weight convert: fp32 -> split bf16 (hi+lo), transposed to [N][K] ----------------
__global__ void k_convert(const float* __restrict__ k0, const float* __restrict__ r0,
                          const float* __restrict__ k1, const float* __restrict__ r1,
                          const float* __restrict__ W,
                          __bf16* __restrict__ wB0Th, __bf16* __restrict__ wB0Tl,  // [2048][640]
                          __bf16* __restrict__ wB1Th, __bf16* __restrict__ wB1Tl,  // [2048][1024]
                          __bf16* __restrict__ wWTh,  __bf16* __restrict__ wWTl)   // [128][512]
{
    int tid = blockIdx.x * blockDim.x + threadIdx.x;
    int nth = gridDim.x * blockDim.x;
    for (int idx = tid; idx < 640 * 2048; idx += nth) {
        int k = idx >> 11, n = idx & 2047;
        float v = (k < 128) ? k0[k * 2048 + n] : r0[(k - 128) * 2048 + n];
        split2(v, wB0Th[n * 640 + k], wB0Tl[n * 640 + k]);
    }
    for (int idx = tid; idx < 1024 * 2048; idx += nth) {
        int k = idx >> 11, n = idx & 2047;
        float v = (k < 512) ? k1[k * 2048 + n] : r1[(k - 512) * 2048 + n];
        split2(v, wB1Th[n * 1024 + k], wB1Tl[n * 1024 + k]);
    }
    for (int idx = tid; idx < 512 * 128; idx += nth) {
        int k = idx >> 7, n = idx & 127;
        split2(W[k * 128 + n], wWTh[n * 512 + k], wWTl[n * 512 + k]);
    }
}

// ---------------- init: cur = x[:,0,:] (split), zero h/c state, zero barrier counters --------
__global__ void k_init(const float* __restrict__ x,
                       __bf16* __restrict__ curh, __bf16* __restrict__ curl,
                       __bf16* __restrict__ h0ah, __bf16* __restrict__ h0al,
                       __bf16* __restrict__ h0bh, __bf16* __restrict__ h0bl,
                       __bf16* __restrict__ h1ah, __bf16* __restrict__ h1al,
                       __bf16* __restrict__ h1bh, __bf16* __restrict__ h1bl,
                       float* __restrict__ c0, float* __restrict__ c1,
                       int* __restrict__ cnt)
{
    int tid = blockIdx.x * blockDim.x + threadIdx.x;
    int nth = gridDim.x * blockDim.x;
    if (tid < 1024) cnt[tid] = 0;
    for (int idx = tid; idx < B_ * D_; idx += nth) {
        int b = idx >> 7, d = idx & 127;
        split2(x[b * (T_ * D_) + d], curh[idx], curl[idx]);  // t=0: missing stays 128.0 exactly
    }
    for (int idx = tid; idx < B_ * H_; idx += nth) {
        h0ah[idx] = (__bf16)0.f; h0al[idx] = (__bf16)0.f;
        h0bh[idx] = (__bf16)0.f; h0bl[idx] = (__bf16)0.f;
        h1ah[idx] = (__bf16)0.f; h1al[idx] = (__bf16)0.f;
        h1bh[idx] = (__bf16)0.f; h1bl[idx] = (__bf16)0.f;
        c0[idx] = 0.f; c1[idx] = 0.f;
    }
}

// ---------------- fence-free grid barrier (r5-proven): vmcnt-drain release + counter ------
__device__ __forceinline__ void gbar(int* cnt, int k) {
    asm volatile("s_waitcnt vmcnt(0)" ::: "memory");
    __syncthreads();
    if (threadIdx.x == 0) {
        __hip_atomic_fetch_add(&cnt[k], 1, __ATOMIC_RELAXED, __HIP_MEMORY_SCOPE_AGENT);
        while (__hip_atomic_load(&cnt[k], __ATOMIC_RELAXED, __HIP_MEMORY_SCOPE_AGENT) < 256)
            __builtin_amdgcn_s_sleep(1);
    }
    __syncthreads();
}

// ---------------- layer phase: B via LDS (local-L2, warm), A direct-to-fragment agent loads ----
// z^T fragment via swapped MFMA (r5/r6-verified): lane owns row m0+wpair*16+(lane&15) and
// 4 consecutive cols j0+(lane>>4)*4..+3.  8 waves: wpair row-group, ksub K-half. BK=128.
// A-amp = 1 (each state element loaded once per phase).  B swizzled LDS (r6-verified).
template <int KTOT, int K1>
__device__ __forceinline__ void layer_phase(
    const __bf16* __restrict__ A1h, const __bf16* __restrict__ A1l, int lda1,
    const __bf16* __restrict__ A2h, const __bf16* __restrict__ A2l, int lda2,
    const __bf16* __restrict__ BTh, const __bf16* __restrict__ BTl,
    const float* __restrict__ bias,
    float* __restrict__ cst,
    __bf16* __restrict__ houth, __bf16* __restrict__ houtl,
    float* __restrict__ hout_f32,
    int j0, int m0, char* smem)
{
    constexpr int LSTR = 144;
    __bf16* sBh = (__bf16*)smem;                 // [64][144]
    __bf16* sBl = sBh + 64 * LSTR;
    float* szred = (float*)smem;                 // aliased after K-loop (barrier-separated)

    const int tid = threadIdx.x;
    const int lane = tid & 63;
    const int wave = tid >> 6;
    const int wpair = wave >> 1;
    const int ksub = wave & 1;

    // B staging (r6 pattern): thread -> (row, 16-elem chunk), XOR swizzle
    const int srow = tid >> 3;
    const int skc = (tid & 7) << 4;
    const int swz = (srow & 7) << 3;
    const int sw1 = srow * LSTR + (skc ^ swz);
    const int sw2 = srow * LSTR + ((skc + 8) ^ swz);
    const int bgrow = (srow >> 4) * 512 + j0 + (srow & 15);

    uint4 rB0, rB1, rBl0, rBl1;
    auto loadB = [&](int kb) {
        size_t off = (size_t)bgrow * KTOT + kb + skc;
        rB0 = *reinterpret_cast<const uint4*>(BTh + off);
        rB1 = *reinterpret_cast<const uint4*>(BTh + off + 8);
        rBl0 = *reinterpret_cast<const uint4*>(BTl + off);
        rBl1 = *reinterpret_cast<const uint4*>(BTl + off + 8);
    };

    // A fragments: contiguous 16B per lane, agent loads, prefetch one iter ahead
    const int arow = m0 + wpair * 16 + (lane & 15);
    const int kfb = ksub * 64 + ((lane >> 4) << 3);
    union AF { u64 u[2]; bf16x8 v; };
    AF aHc[2], aLc[2], aHn[2], aLn[2];
    auto loadA = [&](int kb, AF* aH, AF* aL) {
#pragma unroll
        for (int kk = 0; kk < 2; ++kk) {
            int k = kb + kfb + kk * 32;
            const __bf16 *ah, *al; size_t off;
            if (k < K1) { ah = A1h; al = A1l; off = (size_t)arow * lda1 + k; }
            else        { ah = A2h; al = A2l; off = (size_t)arow * lda2 + (k - K1); }
            aH[kk].u[0] = cload(ah + off); aH[kk].u[1] = cload(ah + off + 4);
            aL[kk].u[0] = cload(al + off); aL[kk].u[1] = cload(al + off + 4);
        }
    };

    loadB(0); loadA(0, aHc, aLc);
    f32x4 acc[4] = {};

    for (int kb = 0; kb < KTOT; kb += 128) {
        __syncthreads();
        *reinterpret_cast<uint4*>(&sBh[sw1]) = rB0;
        *reinterpret_cast<uint4*>(&sBh[sw2]) = rB1;
        *reinterpret_cast<uint4*>(&sBl[sw1]) = rBl0;
        *reinterpret_cast<uint4*>(&sBl[sw2]) = rBl1;
        if (kb + 128 < KTOT) { loadB(kb + 128); loadA(kb + 128, aHn, aLn); }
        __syncthreads();
#pragma unroll
        for (int kk = 0; kk < 2; ++kk) {
            int ko = kfb + kk * 32;
            bf16x8 a_h = aHc[kk].v;
            bf16x8 a_l = aLc[kk].v;
#pragma unroll
            for (int g = 0; g < 4; ++g) {
                int br = g * 16 + (lane & 15);
                int bi = br * LSTR + (ko ^ ((br & 7) << 3));
                bf16x8 b_h = *reinterpret_cast<const bf16x8*>(&sBh[bi]);
                bf16x8 b_l = *reinterpret_cast<const bf16x8*>(&sBl[bi]);
                acc[g] = __builtin_amdgcn_mfma_f32_16x16x32_bf16(b_h, a_h, acc[g], 0, 0, 0);
                acc[g] = __builtin_amdgcn_mfma_f32_16x16x32_bf16(b_l, a_h, acc[g], 0, 0, 0);
                acc[g] = __builtin_amdgcn_mfma_f32_16x16x32_bf16(b_h, a_l, acc[g], 0, 0, 0);
            }
        }
#pragma unroll
        for (int kk = 0; kk < 2; ++kk) { aHc[kk] = aHn[kk]; aLc[kk] = aLn[kk]; }
    }

    __syncthreads();                      // B reads done; szred may alias
    if (ksub == 1) {
        float* zr = &szred[(wpair * 64 + lane) * 21];
#pragma unroll
        for (int g = 0; g < 4; ++g)
#pragma unroll
            for (int r = 0; r < 4; ++r)
                zr[g * 4 + r] = acc[g][r];
    }
    __syncthreads();
    if (ksub == 0) {
        const int row  = m0 + wpair * 16 + (lane & 15);
        const int colb = j0 + ((lane >> 4) << 2);
        const float* zr = &szred[(wpair * 64 + lane) * 21];
        f32x4 bi4 = *reinterpret_cast<const f32x4*>(&bias[colb]);
        f32x4 bf4 = *reinterpret_cast<const f32x4*>(&bias[512 + colb]);
        f32x4 bg4 = *reinterpret_cast<const f32x4*>(&bias[1024 + colb]);
        f32x4 bo4 = *reinterpret_cast<const f32x4*>(&bias[1536 + colb]);
        f32x4 c4 = *reinterpret_cast<f32x4*>(&cst[row * H_ + colb]);
        union { __bf16 b[4]; u64 u; } hh, hl;
        f32x4 h4;
#pragma unroll
        for (int r = 0; r < 4; ++r) {
            float zi = acc[0][r] + zr[0 + r] + bi4[r];
            float zf = acc[1][r] + zr[4 + r] + bf4[r];
            float zg = acc[2][r] + zr[8 + r] + bg4[r];
            float zo = acc[3][r] + zr[12 + r] + bo4[r];
            float gi = sigm(zi), gf = sigm(zf), gg = tanh_(zg), go = sigm(zo);
            float c = gf * c4[r] + gi * gg;
            c4[r] = c;
            float h = go * tanh_(c);
            h4[r] = h;
            split2(h, hh.b[r], hl.b[r]);
        }
        *reinterpret_cast<f32x4*>(&cst[row * H_ + colb]) = c4;   // WG-pinned: plain, L2-local
        cstore(&houth[row * H_ + colb], hh.u);                    // crosses XCDs: coherent
        cstore(&houtl[row * H_ + colb], hl.u);
        if (hout_f32) *reinterpret_cast<f32x4*>(&hout_f32[row * H_ + colb]) = h4;
    }
}

// ---------------- pred phase: one 16x16 tile/WG, 8-wave K-split, direct frag loads ----------
__device__ __forceinline__ void pred_phase(
    const __bf16* __restrict__ h1ph, const __bf16* __restrict__ h1pl,
    const __bf16* __restrict__ WTh, const __bf16* __restrict__ WTl,
    const float* __restrict__ bout, const float* __restrict__ x, int t,
    __bf16* __restrict__ curh, __bf16* __restrict__ curl,
    float* __restrict__ outPred, int wg, char* smem)
{
    float* sred = (float*)smem;
    const int tid = threadIdx.x;
    const int wave = tid >> 6, l = tid & 63;
    const int pr = wg >> 3;
    const int pc = wg & 7;
    const int arow = (pr * 16 + (l & 15)) * 512;
    const int brow = (pc * 16 + (l & 15)) * 512;
    const int kof = (l >> 4) << 3;

    union AF { u64 u[2]; bf16x8 v; };
    f32x4 acc = {};
#pragma unroll
    for (int kk = 0; kk < 2; ++kk) {
        int k = wave * 64 + kk * 32 + kof;
        AF ah, al;
        ah.u[0] = cload(h1ph + arow + k); ah.u[1] = cload(h1ph + arow + k + 4);
        al.u[0] = cload(h1pl + arow + k); al.u[1] = cload(h1pl + arow + k + 4);
        bf16x8 bh = *reinterpret_cast<const bf16x8*>(WTh + brow + k);
        bf16x8 bl = *reinterpret_cast<const bf16x8*>(WTl + brow + k);
        acc = __builtin_amdgcn_mfma_f32_16x16x32_bf16(bh, ah.v, acc, 0, 0, 0);
        acc = __builtin_amdgcn_mfma_f32_16x16x32_bf16(bl, ah.v, acc, 0, 0, 0);
        acc = __builtin_amdgcn_mfma_f32_16x16x32_bf16(bh, al.v, acc, 0, 0, 0);
    }
    {
        float* sr = &sred[(wave * 64 + l) * 5];
#pragma unroll
        for (int r = 0; r < 4; ++r) sr[r] = acc[r];
    }
    __syncthreads();
    if (wave == 0) {
#pragma unroll
        for (int w = 1; w < 8; ++w) {
            const float* sr = &sred[(w * 64 + l) * 5];
#pragma unroll
            for (int r = 0; r < 4; ++r) acc[r] += sr[r];
        }
        const int b = pr * 16 + (l & 15);
        const int colb = pc * 16 + ((l >> 4) << 2);
        f32x4 bo4 = *reinterpret_cast<const f32x4*>(&bout[colb]);
        f32x4 xv4 = *reinterpret_cast<const f32x4*>(&x[((size_t)b * T_ + t) * D_ + colb]);
        f32x4 p4;
        union { __bf16 bb[4]; u64 u; } ch, cl;
#pragma unroll
        for (int r = 0; r < 4; ++r) {
            float pred = acc[r] + bo4[r];
            p4[r] = pred;
            float cv = (xv4[r] == 128.0f) ? pred : xv4[r];
            split2(cv, ch.bb[r], cl.bb[r]);
        }
        *reinterpret_cast<f32x4*>(&outPred[((size_t)b * (T_ - 1) + (t - 1)) * D_ + colb]) = p4;
        cstore(&curh[b * D_ + colb], ch.u);
        cstore(&curl[b * D_ + colb], cl.u);
    }
}

// ---------------- persistent kernel: whole T-loop ----------------
struct KArgs {
    const float* x;
    const __bf16 *wB0Th, *wB0Tl, *wB1Th, *wB1Tl, *wWTh, *wWTl;
    const float *b0, *b1, *bo;
    __bf16 *curh, *curl;
    __bf16 *h0h0, *h0l0, *h0h1, *h0l1;
    __bf16 *h1h0, *h1l0, *h1h1, *h1l1;
    float *c0, *c1;
    float *outPred, *lastcell;
    int* cnt;
};

__global__ __launch_bounds__(512) void k_persistent(KArgs a)
{
    __shared__ __align__(16) char smem[40960];

    const int wg = blockIdx.x;
    const int j0 = (wg & 31) * 16;
    const int m0 = (wg >> 5) * 64;

    __bf16* h0h[2] = { a.h0h0, a.h0h1 };
    __bf16* h0l[2] = { a.h0l0, a.h0l1 };
    __bf16* h1h[2] = { a.h1h0, a.h1h1 };
    __bf16* h1l[2] = { a.h1l0, a.h1l1 };

    int bk = 0;
    for (int t = 0; t < T_; ++t) {
        int cu = t & 1, pv = cu ^ 1;
        if (t > 0) {
            pred_phase(h1h[pv], h1l[pv], a.wWTh, a.wWTl, a.bo, a.x, t,
                       a.curh, a.curl, a.outPred, wg, smem);
            gbar(a.cnt, ++bk);
        }
        layer_phase<640, 128>(a.curh, a.curl, D_, h0h[pv], h0l[pv], H_,
                              a.wB0Th, a.wB0Tl, a.b0, a.c0,
                              h0h[cu], h0l[cu], nullptr, j0, m0, smem);
        gbar(a.cnt, ++bk);
        layer_phase<1024, 512>(h0h[cu], h0l[cu], H_, h1h[pv], h1l[pv], H_,
                               a.wB1Th, a.wB1Tl, a.b1, a.c1,
                               h1h[cu], h1l[cu],
                               (t == T_ - 1) ? a.lastcell : nullptr, j0, m0, smem);
        gbar(a.cnt, ++bk);
    }
}

extern "C" void kernel_launch(void* const* d_in, const int* in_sizes, int n_in,
                              void* d_out, int out_size, void* d_ws, size_t ws_size,
                              hipStream_t stream)
{
    const float* x  = (const float*)d_in[0];
    const float* k0 = (const float*)d_in[1];
    const float* r0 = (const float*)d_in[2];
    const float* b0 = (const float*)d_in[3];
    const float* k1 = (const float*)d_in[4];
    const float* r1 = (const float*)d_in[5];
    const float* b1 = (const float*)d_in[6];
    const float* W  = (const float*)d_in[7];
    const float* bo = (const float*)d_in[8];
    float* out = (float*)d_out;

    char* ws = (char*)d_ws;
    size_t off = 0;
    auto alloc = [&](size_t bytes) { void* p = ws + off; off += (bytes + 255) & ~255ull; return p; };
    __bf16* wB0Th = (__bf16*)alloc((size_t)2048 * 640 * 2);
    __bf16* wB0Tl = (__bf16*)alloc((size_t)2048 * 640 * 2);
    __bf16* wB1Th = (__bf16*)alloc((size_t)2048 * 1024 * 2);
    __bf16* wB1Tl = (__bf16*)alloc((size_t)2048 * 1024 * 2);
    __bf16* wWTh  = (__bf16*)alloc((size_t)128 * 512 * 2);
    __bf16* wWTl  = (__bf16*)alloc((size_t)128 * 512 * 2);
    __bf16* curh  = (__bf16*)alloc((size_t)B_ * D_ * 2);
    __bf16* curl  = (__bf16*)alloc((size_t)B_ * D_ * 2);
    __bf16* h0h[2] = { (__bf16*)alloc((size_t)B_ * H_ * 2), (__bf16*)alloc((size_t)B_ * H_ * 2) };
    __bf16* h0l[2] = { (__bf16*)alloc((size_t)B_ * H_ * 2), (__bf16*)alloc((size_t)B_ * H_ * 2) };
    __bf16* h1h[2] = { (__bf16*)alloc((size_t)B_ * H_ * 2), (__bf16*)alloc((size_t)B_ * H_ * 2) };
    __bf16* h1l[2] = { (__bf16*)alloc((size_t)B_ * H_ * 2), (__bf16*)alloc((size_t)B_ * H_ * 2) };
    float* c0 = (float*)alloc((size_t)B_ * H_ * 4);
    float* c1 = (float*)alloc((size_t)B_ * H_ * 4);
    int* cnt = (int*)alloc(1024 * sizeof(int));

    k_convert<<<2048, 256, 0, stream>>>(k0, r0, k1, r1, W, wB0Th, wB0Tl, wB1Th, wB1Tl, wWTh, wWTl);
    k_init<<<1024, 256, 0, stream>>>(x, curh, curl,
                                     h0h[0], h0l[0], h0h[1], h0l[1],
                                     h1h[0], h1l[0], h1h[1], h1l[1], c0, c1, cnt);

    float* lastcell = out + (size_t)B_ * (T_ - 1) * D_;

    KArgs a;
    a.x = x;
    a.wB0Th = wB0Th; a.wB0Tl = wB0Tl; a.wB1Th = wB1Th; a.wB1Tl = wB1Tl;
    a.wWTh = wWTh; a.wWTl = wWTl;
    a.b0 = b0; a.b1 = b1; a.bo = bo;
    a.curh = curh; a.curl = curl;
    a.h0h0 = h0h[0]; a.h0l0 = h0l[0]; a.h0h1 = h0h[1]; a.h0l1 = h0l[1];
    a.h1h0 = h1h[0]; a.h1l0 = h1l[0]; a.h1h1 = h1h[1]; a.h1l1 = h1l[1];
    a.c0 = c0; a.c1 = c1;
    a.outPred = out; a.lastcell = lastcell;
    a.cnt = cnt;

    void* kargs[] = { &a };
    hipLaunchCooperativeKernel((const void*)k_persistent, dim3(256), dim3(512),
                               kargs, 0, stream);
}